// Round 1
// baseline (458.976 us; speedup 1.0000x reference)
//
#include <hip/hip_runtime.h>
#include <math.h>

#define BB 4
#define CC 256
#define NN 4096
#define KV 32

using half8 = __attribute__((ext_vector_type(8))) _Float16;
using f32x4 = __attribute__((ext_vector_type(4))) float;

__device__ __forceinline__ unsigned short f2h(float f) {
  _Float16 h = (_Float16)f;   // RNE
  return __builtin_bit_cast(unsigned short, h);
}
__device__ __forceinline__ float h2f(unsigned short u) {
  return (float)__builtin_bit_cast(_Float16, u);
}

// async global->LDS DMA, 16B per lane; LDS dest = wave-uniform base + lane*16
#define ASYNC16(g, l)                                                        \
  __builtin_amdgcn_global_load_lds(                                          \
      (const __attribute__((address_space(1))) unsigned int*)(g),            \
      (__attribute__((address_space(3))) unsigned int*)(l), 16, 0, 0)

// XOR bank swizzle at 16B-chunk granularity, rows of 512B (256 fp16)
__device__ __forceinline__ int row512_off(int r, int chunk) {
  return r * 256 + (((chunk & 24) | ((chunk ^ r) & 7)) << 3);
}
// rows of 64B (32 fp16), swizzled in 2-row (128B) units: 8 chunks/unit.
// Each consecutive-8-lane group of a wave ds_read_b128 hits all 8 slots ->
// conflict-free (old per-row swizzle left 8 lanes per 4-bank slot).
__device__ __forceinline__ int tile32_off(int r, int q) {
  return (r >> 1) * 64 + (((((r & 1) << 2) | q) ^ ((r >> 1) & 7)) & 7) * 8;
}
// rows of 128B (64 fp16) — used by k_proj only (unchanged)
__device__ __forceinline__ int vt_off(int r, int chunk) {
  return r * 64 + (((chunk ^ r) & 7) << 3);
}

// ---------------- W pre-cast + pre-tile (unchanged) ----------------
__global__ __launch_bounds__(256) void k_wcast(const float* __restrict__ Wq,
    const float* __restrict__ Wk, const float* __restrict__ Wv,
    unsigned short* __restrict__ Wt) {
  int id = blockIdx.x * 256 + threadIdx.x;     // 24576 chunks
  int pos8 = id & 7, o = (id >> 3) & 255, ks = (id >> 11) & 3, p3 = id >> 13;
  const float* W = p3 == 0 ? Wq : (p3 == 1 ? Wk : Wv);
  int c = ks * 64 + ((pos8 ^ o) & 7) * 8;
  const float* src = W + (size_t)o * CC + c;
  float4 a = *(const float4*)(src);
  float4 b4 = *(const float4*)(src + 4);
  union { unsigned short u[8]; uint4 v4; } pk;
  pk.u[0] = f2h(a.x);  pk.u[1] = f2h(a.y);  pk.u[2] = f2h(a.z);  pk.u[3] = f2h(a.w);
  pk.u[4] = f2h(b4.x); pk.u[5] = f2h(b4.y); pk.u[6] = f2h(b4.z); pk.u[7] = f2h(b4.w);
  *(uint4*)(Wt + (size_t)id * 8) = pk.v4;
}

// ---------------- fused 3-projection kernel (unchanged) ----------------
__global__ __launch_bounds__(512) void k_proj(const float* __restrict__ x,
    const unsigned short* __restrict__ Wt,
    const float* __restrict__ bq, const float* __restrict__ bk,
    const float* __restrict__ bv,
    unsigned short* __restrict__ Q, unsigned short* __restrict__ K,
    unsigned short* __restrict__ V) {
  __shared__ __align__(16) char ps[110848];
  float* xf = (float*)ps;                               // 64 c x 33 f32 (8448 B)
  unsigned short* xa = (unsigned short*)(ps + 8448);    // 32 n x 64 c fp16 (4096 B)
  unsigned short* wh = (unsigned short*)(ps + 12544);   // 3 x 256 o x 64 c fp16 (98304 B)
  int b = blockIdx.y, n0 = blockIdx.x * 32;
  int t = threadIdx.x, w = t >> 6, lane = t & 63, l15 = lane & 15, quad = lane >> 4;

  f32x4 z = {0.f, 0.f, 0.f, 0.f};
  f32x4 acc[3][2][2];   // [proj][ct: 16-o][mt: 16-n]
#pragma unroll
  for (int p3 = 0; p3 < 3; ++p3)
#pragma unroll
    for (int ct = 0; ct < 2; ++ct)
#pragma unroll
      for (int mt = 0; mt < 2; ++mt) acc[p3][ct][mt] = z;

  for (int ks = 0; ks < 4; ++ks) {
    if (ks) __syncthreads();   // all waves done with xa/wh of prev ks
    // W DMA: 3 projs x 32 KB, linear copy of pre-tiled Wt
#pragma unroll
    for (int p3 = 0; p3 < 3; ++p3) {
      const char* wb = (const char*)(Wt + (size_t)(p3 * 4 + ks) * 16384);
#pragma unroll
      for (int p = 0; p < 4; ++p) {
        int c = p * 512 + t;
        ASYNC16(wb + c * 16, &wh[p3 * 16384 + (p * 512 + (w << 6)) * 8]);
      }
    }
    // x f32 tile: 64 c-rows x 32 n, coalesced 16B loads
    {
      int c = t >> 3, nl = (t & 7) * 4;
      float4 v = *(const float4*)(x + ((size_t)b * CC + ks * 64 + c) * NN + n0 + nl);
      float* d = xf + c * 33 + nl;
      d[0] = v.x; d[1] = v.y; d[2] = v.z; d[3] = v.w;
    }
    __syncthreads();   // xf visible; W DMA drained
    // transpose-pack: xa[n][c] fp16 (A-layout, swizzled), once per ks
    {
      int n = t >> 4, cb = (t & 15) * 4;
      union { unsigned short u[4]; ushort4 v4; } tmp;
#pragma unroll
      for (int i = 0; i < 4; ++i) tmp.u[i] = f2h(xf[(cb + i) * 33 + n]);
      int ch = cb >> 3;
      *(ushort4*)&xa[n * 64 + (((ch ^ n) & 7) << 3) + (cb & 7)] = tmp.v4;
    }
    __syncthreads();   // xa visible
#pragma unroll
    for (int kc = 0; kc < 2; ++kc) {
      half8 af[2];
#pragma unroll
      for (int mt = 0; mt < 2; ++mt)
        af[mt] = *(const half8*)&xa[vt_off(mt * 16 + l15, kc * 4 + quad)];
#pragma unroll
      for (int p3 = 0; p3 < 3; ++p3)
#pragma unroll
        for (int ct = 0; ct < 2; ++ct) {
          half8 bf = *(const half8*)&wh[p3 * 16384 + vt_off(w * 32 + ct * 16 + l15, kc * 4 + quad)];
#pragma unroll
          for (int mt = 0; mt < 2; ++mt)
            acc[p3][ct][mt] = __builtin_amdgcn_mfma_f32_16x16x32_f16(af[mt], bf, acc[p3][ct][mt], 0, 0, 0);
        }
    }
  }
  // bias
#pragma unroll
  for (int p3 = 0; p3 < 3; ++p3) {
    const float* bias = p3 == 0 ? bq : (p3 == 1 ? bk : bv);
#pragma unroll
    for (int ct = 0; ct < 2; ++ct) {
      float bv_ = bias[w * 32 + ct * 16 + l15];
#pragma unroll
      for (int mt = 0; mt < 2; ++mt)
#pragma unroll
        for (int r = 0; r < 4; ++r) acc[p3][ct][mt][r] += bv_;
    }
  }
  // epilogues: Q, K via qo[32][264]; V via vo[256][36]
#pragma unroll
  for (int p3 = 0; p3 < 2; ++p3) {
    __syncthreads();
    unsigned short* qo = (unsigned short*)ps;   // 32 x 264
#pragma unroll
    for (int ct = 0; ct < 2; ++ct)
#pragma unroll
      for (int mt = 0; mt < 2; ++mt)
#pragma unroll
        for (int r = 0; r < 4; ++r)
          qo[(mt * 16 + quad * 4 + r) * 264 + w * 32 + ct * 16 + l15] = f2h(acc[p3][ct][mt][r]);
    __syncthreads();
    unsigned short* outp = (p3 == 0 ? Q : K) + ((size_t)b * NN + n0) * CC;
#pragma unroll
    for (int p = 0; p < 2; ++p) {
      int f = p * 8192 + t * 16;
      int n = f >> 9, off = f & 511;
      *(uint4*)((char*)outp + (size_t)n * 512 + off) =
        *(const uint4*)((const char*)&qo[n * 264] + off);
    }
  }
  {
    __syncthreads();
    unsigned short* vo = (unsigned short*)ps;   // 256 x 36
#pragma unroll
    for (int ct = 0; ct < 2; ++ct)
#pragma unroll
      for (int mt = 0; mt < 2; ++mt)
#pragma unroll
        for (int r = 0; r < 4; ++r)
          vo[(w * 32 + ct * 16 + l15) * 36 + mt * 16 + quad * 4 + r] = f2h(acc[2][ct][mt][r]);
    __syncthreads();
#pragma unroll
    for (int p = 0; p < 2; ++p) {
      int id = p * 512 + t;
      int o = id >> 2, off = (id & 3) * 16;
      *(uint4*)((char*)(V + ((size_t)b * CC + o) * NN + n0) + off) =
        *(const uint4*)((const char*)&vo[o * 36] + off);
    }
  }
}

// ---------------- flash attention: KV=32 tiles, 57KB LDS -> 2 blocks/CU ------
__global__ __launch_bounds__(512, 4) void k_flash(const unsigned short* __restrict__ Q,
    const unsigned short* __restrict__ K, const unsigned short* __restrict__ V,
    float* __restrict__ out, unsigned short* __restrict__ opart,
    float* __restrict__ ml, int n_splits) {
  __shared__ __align__(16) char sm[58368];
  unsigned short* kt0 = (unsigned short*)sm;            // 16KB: 32 k x 256 c
  unsigned short* kt1 = (unsigned short*)(sm + 16384);  // 16KB
  unsigned short* vt  = (unsigned short*)(sm + 32768);  // 16KB: 256 c x 32 k
  unsigned short* pt  = (unsigned short*)(sm + 49152);  // 8KB: 128 q x 32 k
  float* al = (float*)(sm + 57344);
  float* ll = (float*)(sm + 57856);
  int b = blockIdx.y, q0 = blockIdx.x * 128, split = blockIdx.z;
  int nt = (NN / KV) / n_splits;
  int t = threadIdx.x, w = t >> 6, lane = t & 63, l15 = lane & 15, quad = lane >> 4;
  int g = w >> 1, h = w & 1;

  half8 qf[8];
  const unsigned short* qrow = Q + ((size_t)b * NN + q0 + w * 16 + l15) * CC;
#pragma unroll
  for (int k = 0; k < 8; ++k) qf[k] = *(const half8*)(qrow + k * 32 + quad * 8);

  f32x4 z = {0.f, 0.f, 0.f, 0.f};
  f32x4 o_acc[2][8];   // 32 q x 128 c per wave (PV role)
#pragma unroll
  for (int mt = 0; mt < 2; ++mt)
#pragma unroll
    for (int i = 0; i < 8; ++i) o_acc[mt][i] = z;
  float m_i[4], lp_[4];
#pragma unroll
  for (int r = 0; r < 4; ++r) { m_i[r] = -INFINITY; lp_[r] = 0.f; }

  int it_beg = split * nt, it_end = it_beg + nt;

  auto dma_k = [&](int it, unsigned short* dst) {
    const char* kb = (const char*)(K + ((size_t)b * NN + it * KV) * CC);
#pragma unroll
    for (int p = 0; p < 2; ++p) {
      int c = p * 512 + t;          // chunk 0..1023
      int r = c >> 5, lo = c & 31;
      int ch = (lo & 24) | ((lo ^ r) & 7);
      ASYNC16(kb + r * 512 + ch * 16, &dst[(p * 512 + (w << 6)) * 8]);
    }
  };
  auto dma_v = [&](int it) {
    const char* vb = (const char*)(V + (size_t)b * CC * NN + it * KV);
#pragma unroll
    for (int p = 0; p < 2; ++p) {
      int id = p * 512 + t;         // chunk 0..1023
      int unit = id >> 3, u = id & 7;
      int x = u ^ (unit & 7);
      int r = unit * 2 + (x >> 2), ch = x & 3;   // c-row, k-chunk
      ASYNC16(vb + (size_t)r * (NN * 2) + ch * 16, &vt[(p * 512 + (w << 6)) * 8]);
    }
  };

  auto body = [&](const unsigned short* cur, unsigned short* nxt, int it) {
    if (it + 1 < it_end) dma_k(it + 1, nxt);
    dma_v(it);

    f32x4 sa[2];
#pragma unroll
    for (int j = 0; j < 2; ++j) sa[j] = z;
    __builtin_amdgcn_s_setprio(1);
#pragma unroll
    for (int kk = 0; kk < 8; ++kk)
#pragma unroll
      for (int j = 0; j < 2; ++j) {
        half8 bf = *(const half8*)&cur[row512_off(j * 16 + l15, kk * 4 + quad)];
        sa[j] = __builtin_amdgcn_mfma_f32_16x16x32_f16(qf[kk], bf, sa[j], 0, 0, 0);
      }
    __builtin_amdgcn_s_setprio(0);
    float mt4[4];
#pragma unroll
    for (int r = 0; r < 4; ++r) mt4[r] = fmaxf(sa[0][r], sa[1][r]);
#pragma unroll
    for (int off = 1; off < 16; off <<= 1)
#pragma unroll
      for (int r = 0; r < 4; ++r)
        mt4[r] = fmaxf(mt4[r], __shfl_xor(mt4[r], off, 64));
    float alpha[4];
#pragma unroll
    for (int r = 0; r < 4; ++r) {
      float mn = fmaxf(m_i[r], mt4[r]);
      alpha[r] = __expf(m_i[r] - mn);
      m_i[r] = mn;
    }
#pragma unroll
    for (int r = 0; r < 4; ++r) {
      float ls = 0.f;
#pragma unroll
      for (int j = 0; j < 2; ++j) {
        float p = __expf(sa[j][r] - m_i[r]);
        sa[j][r] = p;
        ls += p;
      }
      lp_[r] = lp_[r] * alpha[r] + ls;
    }
    if (l15 == 0) {
#pragma unroll
      for (int r = 0; r < 4; ++r) al[w * 16 + quad * 4 + r] = alpha[r];
    }
#pragma unroll
    for (int j = 0; j < 2; ++j)
#pragma unroll
      for (int r = 0; r < 4; ++r) {
        int row = w * 16 + quad * 4 + r;
        int ch = 2 * j + (l15 >> 3);
        pt[tile32_off(row, ch) + (l15 & 7)] = f2h(sa[j][r]);
      }
    __syncthreads();   // drains both DMAs; P + alpha visible

    float a_al[2][4];
#pragma unroll
    for (int mt = 0; mt < 2; ++mt)
#pragma unroll
      for (int r = 0; r < 4; ++r)
        a_al[mt][r] = al[g * 32 + mt * 16 + quad * 4 + r];
#pragma unroll
    for (int mt = 0; mt < 2; ++mt)
#pragma unroll
      for (int ct = 0; ct < 8; ++ct)
#pragma unroll
        for (int r = 0; r < 4; ++r) o_acc[mt][ct][r] *= a_al[mt][r];
    half8 af[2];
#pragma unroll
    for (int mt = 0; mt < 2; ++mt)
      af[mt] = *(const half8*)&pt[tile32_off(g * 32 + mt * 16 + l15, quad)];
    __builtin_amdgcn_s_setprio(1);
#pragma unroll
    for (int ct = 0; ct < 8; ++ct) {
      half8 bf = *(const half8*)&vt[tile32_off(h * 128 + ct * 16 + l15, quad)];
#pragma unroll
      for (int mt = 0; mt < 2; ++mt)
        o_acc[mt][ct] = __builtin_amdgcn_mfma_f32_16x16x32_f16(af[mt], bf, o_acc[mt][ct], 0, 0, 0);
    }
    __builtin_amdgcn_s_setprio(0);
    __syncthreads();
  };

  dma_k(it_beg, kt0);
  __syncthreads();
  for (int it = it_beg; it < it_end; it += 2) {
    body(kt0, kt1, it);
    body(kt1, kt0, it + 1);
  }

#pragma unroll
  for (int off = 1; off < 16; off <<= 1)
#pragma unroll
    for (int r = 0; r < 4; ++r)
      lp_[r] += __shfl_xor(lp_[r], off, 64);
  if (l15 == 0) {
#pragma unroll
    for (int r = 0; r < 4; ++r) ll[w * 16 + quad * 4 + r] = lp_[r];
  }
  if (n_splits != 1 && l15 == 0) {
    size_t qi = (size_t)q0 + w * 16 + quad * 4;
    float* mp = ml + ((size_t)(split * 2 + 0) * BB + b) * NN + qi;
    float* lq = ml + ((size_t)(split * 2 + 1) * BB + b) * NN + qi;
#pragma unroll
    for (int r = 0; r < 4; ++r) { mp[r] = m_i[r]; lq[r] = lp_[r]; }
  }
  __syncthreads();
  float sc[2][4];
#pragma unroll
  for (int mt = 0; mt < 2; ++mt)
#pragma unroll
    for (int r = 0; r < 4; ++r) {
      float lv = ll[g * 32 + mt * 16 + quad * 4 + r];
      sc[mt][r] = (n_splits == 1) ? 1.f / lv : 1.f;
    }

  float* od = (float*)sm;     // 32 x 132 f32 (16896 B), kt0/kt1 dead
  float* obf = out + (size_t)b * CC * NN + q0;
  unsigned short* obh = opart + ((size_t)split * BB + b) * CC * NN + q0;
#pragma unroll
  for (int pp = 0; pp < 8; ++pp) {
    __syncthreads();
    if (h == (pp >> 2)) {
#pragma unroll
      for (int cp = 0; cp < 2; ++cp) {
        int ct = (pp & 3) * 2 + cp;
#pragma unroll
        for (int mt = 0; mt < 2; ++mt)
#pragma unroll
          for (int r = 0; r < 4; ++r)
            od[(cp * 16 + l15) * 132 + g * 32 + mt * 16 + quad * 4 + r] =
                o_acc[mt][ct][r] * sc[mt][r];
      }
    }
    __syncthreads();
    if (n_splits == 1) {
#pragma unroll
      for (int p2 = 0; p2 < 2; ++p2) {
        int row = p2 * 16 + (t >> 5);
        *(float4*)(obf + (size_t)(pp * 32 + row) * NN + (t & 31) * 4) =
          *(const float4*)&od[row * 132 + (t & 31) * 4];
      }
    } else {
      int row = t >> 4, q8 = (t & 15) * 8;
      union { unsigned short u[8]; uint4 v4; } tmp;
#pragma unroll
      for (int i2 = 0; i2 < 8; ++i2) tmp.u[i2] = f2h(od[row * 132 + q8 + i2]);
      *(uint4*)(obh + (size_t)(pp * 32 + row) * NN + q8) = tmp.v4;
    }
  }
}

// ---------------- merge of NS key-splits ----------------
template <int NS>
__global__ __launch_bounds__(256) void k_merge(const unsigned short* __restrict__ opart,
    const float* __restrict__ ml, float* __restrict__ out) {
  size_t i = ((size_t)blockIdx.x * 256 + threadIdx.x) * 4;
  int n = (int)(i & (NN - 1));
  int b = (int)(i >> 20);   // i / (CC*NN)
  float4 m[NS], l[NS];
  ushort4 o[NS];
#pragma unroll
  for (int s = 0; s < NS; ++s) {
    m[s] = *(const float4*)(ml + ((size_t)(s * 2 + 0) * BB + b) * NN + n);
    l[s] = *(const float4*)(ml + ((size_t)(s * 2 + 1) * BB + b) * NN + n);
    o[s] = *(const ushort4*)(opart + (size_t)s * BB * CC * NN + i);
  }
  float4 res;
#define MRG(f, comp) { \
    float M = m[0].f; \
    _Pragma("unroll") for (int s = 1; s < NS; ++s) M = fmaxf(M, m[s].f); \
    float num = 0.f, den = 0.f; \
    _Pragma("unroll") for (int s = 0; s < NS; ++s) { \
      float e = __expf(m[s].f - M); \
      num += e * h2f(o[s].comp); den += e * l[s].f; } \
    res.f = num / den; }
  MRG(x, x) MRG(y, y) MRG(z, z) MRG(w, w)
#undef MRG
  *(float4*)(out + i) = res;
}

extern "C" void kernel_launch(void* const* d_in, const int* in_sizes, int n_in,
                              void* d_out, int out_size, void* d_ws, size_t ws_size,
                              hipStream_t stream) {
  const float* x  = (const float*)d_in[0];
  const float* Wq = (const float*)d_in[1];
  const float* bq = (const float*)d_in[2];
  const float* Wk = (const float*)d_in[3];
  const float* bk = (const float*)d_in[4];
  const float* Wv = (const float*)d_in[5];
  const float* bv = (const float*)d_in[6];
  float* out = (float*)d_out;
  char* ws = (char*)d_ws;
  const size_t MB = 1024 * 1024;
  unsigned short* Qb = (unsigned short*)(ws);             // 8 MB fp16 (B,N,C)
  unsigned short* Kb = (unsigned short*)(ws + 8 * MB);    // 8 MB fp16 (B,N,C)
  unsigned short* Vb = (unsigned short*)(ws + 16 * MB);   // 8 MB fp16 (B,C,N)
  unsigned short* Op = (unsigned short*)(ws + 24 * MB);   // ns x 8 MB fp16 partials

  // ns=4 needs 24 + 32 + 0.5 (Ml) + 0.375 (Wt) = 56.875 MB
  int ns = (ws_size >= 57 * MB) ? 4 : (ws_size >= 41 * MB ? 2 : 1);
  float* Ml;
  unsigned short* Wt;
  if (ns == 4) {
    Ml = (float*)(ws + 56 * MB);                          // 512 KB
    Wt = (unsigned short*)(ws + 56 * MB + 512 * 1024);    // 384 KB
  } else if (ns == 2) {
    Ml = (float*)(ws + 40 * MB);                          // 256 KB
    Wt = (unsigned short*)(ws + 40 * MB + 256 * 1024);
  } else {
    Ml = (float*)(ws + 24 * MB);                          // unused
    Wt = (unsigned short*)(ws + 24 * MB);
  }

  k_wcast<<<dim3(96), 256, 0, stream>>>(Wq, Wk, Wv, Wt);
  k_proj<<<dim3(128, 4), 512, 0, stream>>>(x, Wt, bq, bk, bv, Qb, Kb, Vb);

  k_flash<<<dim3(32, 4, ns), 512, 0, stream>>>(Qb, Kb, Vb, out, Op, Ml, ns);
  if (ns == 4)      k_merge<4><<<dim3(4096), 256, 0, stream>>>(Op, Ml, out);
  else if (ns == 2) k_merge<2><<<dim3(4096), 256, 0, stream>>>(Op, Ml, out);
}

// Round 2
// 233.995 us; speedup vs baseline: 1.9615x; 1.9615x over previous
//
#include <hip/hip_runtime.h>
#include <math.h>

#define BB 4
#define CC 256
#define NN 4096
#define KV 32

using half8 = __attribute__((ext_vector_type(8))) _Float16;
using f32x4 = __attribute__((ext_vector_type(4))) float;

__device__ __forceinline__ unsigned short f2h(float f) {
  _Float16 h = (_Float16)f;   // RNE
  return __builtin_bit_cast(unsigned short, h);
}
__device__ __forceinline__ float h2f(unsigned short u) {
  return (float)__builtin_bit_cast(_Float16, u);
}

// async global->LDS DMA, 16B per lane; LDS dest = wave-uniform base + lane*16
#define ASYNC16(g, l)                                                        \
  __builtin_amdgcn_global_load_lds(                                          \
      (const __attribute__((address_space(1))) unsigned int*)(g),            \
      (__attribute__((address_space(3))) unsigned int*)(l), 16, 0, 0)

// XOR bank swizzle at 16B-chunk granularity, rows of 512B (256 fp16)
__device__ __forceinline__ int row512_off(int r, int chunk) {
  return r * 256 + (((chunk & 24) | ((chunk ^ r) & 7)) << 3);
}
// rows of 64B (32 fp16), swizzled in 2-row (128B) units: 8 chunks/unit.
// (correctness-verified in the previous passing run)
__device__ __forceinline__ int tile32_off(int r, int q) {
  return (r >> 1) * 64 + (((((r & 1) << 2) | q) ^ ((r >> 1) & 7)) & 7) * 8;
}
// rows of 128B (64 fp16) — used by k_proj only
__device__ __forceinline__ int vt_off(int r, int chunk) {
  return r * 64 + (((chunk ^ r) & 7) << 3);
}

// ---------------- W pre-cast + pre-tile (unchanged) ----------------
__global__ __launch_bounds__(256) void k_wcast(const float* __restrict__ Wq,
    const float* __restrict__ Wk, const float* __restrict__ Wv,
    unsigned short* __restrict__ Wt) {
  int id = blockIdx.x * 256 + threadIdx.x;     // 24576 chunks
  int pos8 = id & 7, o = (id >> 3) & 255, ks = (id >> 11) & 3, p3 = id >> 13;
  const float* W = p3 == 0 ? Wq : (p3 == 1 ? Wk : Wv);
  int c = ks * 64 + ((pos8 ^ o) & 7) * 8;
  const float* src = W + (size_t)o * CC + c;
  float4 a = *(const float4*)(src);
  float4 b4 = *(const float4*)(src + 4);
  union { unsigned short u[8]; uint4 v4; } pk;
  pk.u[0] = f2h(a.x);  pk.u[1] = f2h(a.y);  pk.u[2] = f2h(a.z);  pk.u[3] = f2h(a.w);
  pk.u[4] = f2h(b4.x); pk.u[5] = f2h(b4.y); pk.u[6] = f2h(b4.z); pk.u[7] = f2h(b4.w);
  *(uint4*)(Wt + (size_t)id * 8) = pk.v4;
}

// ---------------- fused 3-projection kernel (unchanged) ----------------
__global__ __launch_bounds__(512) void k_proj(const float* __restrict__ x,
    const unsigned short* __restrict__ Wt,
    const float* __restrict__ bq, const float* __restrict__ bk,
    const float* __restrict__ bv,
    unsigned short* __restrict__ Q, unsigned short* __restrict__ K,
    unsigned short* __restrict__ V) {
  __shared__ __align__(16) char ps[110848];
  float* xf = (float*)ps;                               // 64 c x 33 f32 (8448 B)
  unsigned short* xa = (unsigned short*)(ps + 8448);    // 32 n x 64 c fp16 (4096 B)
  unsigned short* wh = (unsigned short*)(ps + 12544);   // 3 x 256 o x 64 c fp16 (98304 B)
  int b = blockIdx.y, n0 = blockIdx.x * 32;
  int t = threadIdx.x, w = t >> 6, lane = t & 63, l15 = lane & 15, quad = lane >> 4;

  f32x4 z = {0.f, 0.f, 0.f, 0.f};
  f32x4 acc[3][2][2];   // [proj][ct: 16-o][mt: 16-n]
#pragma unroll
  for (int p3 = 0; p3 < 3; ++p3)
#pragma unroll
    for (int ct = 0; ct < 2; ++ct)
#pragma unroll
      for (int mt = 0; mt < 2; ++mt) acc[p3][ct][mt] = z;

  for (int ks = 0; ks < 4; ++ks) {
    if (ks) __syncthreads();   // all waves done with xa/wh of prev ks
    // W DMA: 3 projs x 32 KB, linear copy of pre-tiled Wt
#pragma unroll
    for (int p3 = 0; p3 < 3; ++p3) {
      const char* wb = (const char*)(Wt + (size_t)(p3 * 4 + ks) * 16384);
#pragma unroll
      for (int p = 0; p < 4; ++p) {
        int c = p * 512 + t;
        ASYNC16(wb + c * 16, &wh[p3 * 16384 + (p * 512 + (w << 6)) * 8]);
      }
    }
    // x f32 tile: 64 c-rows x 32 n, coalesced 16B loads
    {
      int c = t >> 3, nl = (t & 7) * 4;
      float4 v = *(const float4*)(x + ((size_t)b * CC + ks * 64 + c) * NN + n0 + nl);
      float* d = xf + c * 33 + nl;
      d[0] = v.x; d[1] = v.y; d[2] = v.z; d[3] = v.w;
    }
    __syncthreads();   // xf visible; W DMA drained
    // transpose-pack: xa[n][c] fp16 (A-layout, swizzled), once per ks
    {
      int n = t >> 4, cb = (t & 15) * 4;
      union { unsigned short u[4]; ushort4 v4; } tmp;
#pragma unroll
      for (int i = 0; i < 4; ++i) tmp.u[i] = f2h(xf[(cb + i) * 33 + n]);
      int ch = cb >> 3;
      *(ushort4*)&xa[n * 64 + (((ch ^ n) & 7) << 3) + (cb & 7)] = tmp.v4;
    }
    __syncthreads();   // xa visible
#pragma unroll
    for (int kc = 0; kc < 2; ++kc) {
      half8 af[2];
#pragma unroll
      for (int mt = 0; mt < 2; ++mt)
        af[mt] = *(const half8*)&xa[vt_off(mt * 16 + l15, kc * 4 + quad)];
#pragma unroll
      for (int p3 = 0; p3 < 3; ++p3)
#pragma unroll
        for (int ct = 0; ct < 2; ++ct) {
          half8 bf = *(const half8*)&wh[p3 * 16384 + vt_off(w * 32 + ct * 16 + l15, kc * 4 + quad)];
#pragma unroll
          for (int mt = 0; mt < 2; ++mt)
            acc[p3][ct][mt] = __builtin_amdgcn_mfma_f32_16x16x32_f16(af[mt], bf, acc[p3][ct][mt], 0, 0, 0);
        }
    }
  }
  // bias
#pragma unroll
  for (int p3 = 0; p3 < 3; ++p3) {
    const float* bias = p3 == 0 ? bq : (p3 == 1 ? bk : bv);
#pragma unroll
    for (int ct = 0; ct < 2; ++ct) {
      float bv_ = bias[w * 32 + ct * 16 + l15];
#pragma unroll
      for (int mt = 0; mt < 2; ++mt)
#pragma unroll
        for (int r = 0; r < 4; ++r) acc[p3][ct][mt][r] += bv_;
    }
  }
  // epilogues: Q, K via qo[32][264]; V via vo[256][36]
#pragma unroll
  for (int p3 = 0; p3 < 2; ++p3) {
    __syncthreads();
    unsigned short* qo = (unsigned short*)ps;   // 32 x 264
#pragma unroll
    for (int ct = 0; ct < 2; ++ct)
#pragma unroll
      for (int mt = 0; mt < 2; ++mt)
#pragma unroll
        for (int r = 0; r < 4; ++r)
          qo[(mt * 16 + quad * 4 + r) * 264 + w * 32 + ct * 16 + l15] = f2h(acc[p3][ct][mt][r]);
    __syncthreads();
    unsigned short* outp = (p3 == 0 ? Q : K) + ((size_t)b * NN + n0) * CC;
#pragma unroll
    for (int p = 0; p < 2; ++p) {
      int f = p * 8192 + t * 16;
      int n = f >> 9, off = f & 511;
      *(uint4*)((char*)outp + (size_t)n * 512 + off) =
        *(const uint4*)((const char*)&qo[n * 264] + off);
    }
  }
  {
    __syncthreads();
    unsigned short* vo = (unsigned short*)ps;   // 256 x 36
#pragma unroll
    for (int ct = 0; ct < 2; ++ct)
#pragma unroll
      for (int mt = 0; mt < 2; ++mt)
#pragma unroll
        for (int r = 0; r < 4; ++r)
          vo[(w * 32 + ct * 16 + l15) * 36 + mt * 16 + quad * 4 + r] = f2h(acc[2][ct][mt][r]);
    __syncthreads();
#pragma unroll
    for (int p = 0; p < 2; ++p) {
      int id = p * 512 + t;
      int o = id >> 2, off = (id & 3) * 16;
      *(uint4*)((char*)(V + ((size_t)b * CC + o) * NN + n0) + off) =
        *(const uint4*)((const char*)&vo[o * 36] + off);
    }
  }
}

// ---------------- flash attention: deferred-PV, 1 barrier/body ----------------
// KV=32 tiles, full double-buffer (kt/vt/pt/al x2, 82KB LDS). Body i:
//   barrier -> issue DMA K(i+1),V(i) -> QK^T(i) -> softmax(i)->P(i) -> PV(i-1)
// QK^T(i) and PV(i-1) are independent; every DMA has a full body of cover.
__global__ __launch_bounds__(512) void k_flash(const unsigned short* __restrict__ Q,
    const unsigned short* __restrict__ K, const unsigned short* __restrict__ V,
    float* __restrict__ out, unsigned short* __restrict__ opart,
    float* __restrict__ ml, int n_splits) {
  __shared__ __align__(16) char sm[83456];
  unsigned short* kt0 = (unsigned short*)sm;            // 16KB: 32 k x 256 c
  unsigned short* kt1 = (unsigned short*)(sm + 16384);
  unsigned short* vt0 = (unsigned short*)(sm + 32768);  // 16KB: 256 c x 32 k
  unsigned short* vt1 = (unsigned short*)(sm + 49152);
  unsigned short* pt0 = (unsigned short*)(sm + 65536);  // 8KB: 128 q x 32 k
  unsigned short* pt1 = (unsigned short*)(sm + 73728);
  float* al0 = (float*)(sm + 81920);                    // 128 f32 alpha
  float* al1 = (float*)(sm + 82432);
  float* ll  = (float*)(sm + 82944);                    // 128 f32 lse
  int b = blockIdx.y, q0 = blockIdx.x * 128, split = blockIdx.z;
  int nt = (NN / KV) / n_splits;
  int t = threadIdx.x, w = t >> 6, lane = t & 63, l15 = lane & 15, quad = lane >> 4;
  int g = w >> 1, h = w & 1;

  half8 qf[8];
  const unsigned short* qrow = Q + ((size_t)b * NN + q0 + w * 16 + l15) * CC;
#pragma unroll
  for (int k = 0; k < 8; ++k) qf[k] = *(const half8*)(qrow + k * 32 + quad * 8);

  f32x4 z = {0.f, 0.f, 0.f, 0.f};
  f32x4 o_acc[2][8];   // 32 q x 128 c per wave (PV role)
#pragma unroll
  for (int mt = 0; mt < 2; ++mt)
#pragma unroll
    for (int i = 0; i < 8; ++i) o_acc[mt][i] = z;
  float m_i[4], lp_[4];
#pragma unroll
  for (int r = 0; r < 4; ++r) { m_i[r] = -INFINITY; lp_[r] = 0.f; }

  int it_beg = split * nt, it_end = it_beg + nt;

  auto dma_k = [&](int it, unsigned short* dst) {
    const char* kb = (const char*)(K + ((size_t)b * NN + it * KV) * CC);
#pragma unroll
    for (int p = 0; p < 2; ++p) {
      int c = p * 512 + t;          // chunk 0..1023
      int r = c >> 5, lo = c & 31;
      int ch = (lo & 24) | ((lo ^ r) & 7);
      ASYNC16(kb + r * 512 + ch * 16, &dst[(p * 512 + (w << 6)) * 8]);
    }
  };
  auto dma_v = [&](int it, unsigned short* dst) {
    const char* vb = (const char*)(V + (size_t)b * CC * NN + it * KV);
#pragma unroll
    for (int p = 0; p < 2; ++p) {
      int id = p * 512 + t;         // chunk 0..1023
      int unit = id >> 3, u = id & 7;
      int x2 = u ^ (unit & 7);
      int r = unit * 2 + (x2 >> 2), ch = x2 & 3;   // c-row, k-chunk
      ASYNC16(vb + (size_t)r * (NN * 2) + ch * 16, &dst[(p * 512 + (w << 6)) * 8]);
    }
  };

  // PV for tile (it-1): rescale by alpha(it-1) then accumulate P(it-1)V(it-1)
  auto pv_step = [&](const unsigned short* pprev, const unsigned short* vprev,
                     const float* alp) {
    f32x4 aa[2];
    aa[0] = *(const f32x4*)&alp[g * 32 + quad * 4];
    aa[1] = *(const f32x4*)&alp[g * 32 + 16 + quad * 4];
    int need = 0;
#pragma unroll
    for (int mt = 0; mt < 2; ++mt)
#pragma unroll
      for (int r = 0; r < 4; ++r) need |= (aa[mt][r] != 1.f);
    if (__any(need)) {
#pragma unroll
      for (int mt = 0; mt < 2; ++mt)
#pragma unroll
        for (int ct = 0; ct < 8; ++ct)
#pragma unroll
          for (int r = 0; r < 4; ++r) o_acc[mt][ct][r] *= aa[mt][r];
    }
    half8 af[2];
#pragma unroll
    for (int mt = 0; mt < 2; ++mt)
      af[mt] = *(const half8*)&pprev[tile32_off(g * 32 + mt * 16 + l15, quad)];
    __builtin_amdgcn_s_setprio(1);
#pragma unroll
    for (int ct = 0; ct < 8; ++ct) {
      half8 bf = *(const half8*)&vprev[tile32_off(h * 128 + ct * 16 + l15, quad)];
#pragma unroll
      for (int mt = 0; mt < 2; ++mt)
        o_acc[mt][ct] = __builtin_amdgcn_mfma_f32_16x16x32_f16(af[mt], bf, o_acc[mt][ct], 0, 0, 0);
    }
    __builtin_amdgcn_s_setprio(0);
  };

  dma_k(it_beg, (it_beg & 1) ? kt1 : kt0);

  for (int it = it_beg; it < it_end; ++it) {
    int par = it & 1;
    const unsigned short* kcur = par ? kt1 : kt0;
    unsigned short* knxt       = par ? kt0 : kt1;
    unsigned short* vcur       = par ? vt1 : vt0;   // DMA target for V(it)
    const unsigned short* vprev = par ? vt0 : vt1;  // V(it-1)
    unsigned short* pcur       = par ? pt1 : pt0;
    const unsigned short* pprev = par ? pt0 : pt1;
    float* alc       = par ? al1 : al0;
    const float* alp = par ? al0 : al1;

    __syncthreads();   // drains K(it) + V(it-1) DMAs; P(it-1)/alpha(it-1) visible

    if (it + 1 < it_end) dma_k(it + 1, knxt);
    dma_v(it, vcur);

    // ---- QK^T(it) ----
    f32x4 sa[2];
    sa[0] = z; sa[1] = z;
    __builtin_amdgcn_s_setprio(1);
#pragma unroll
    for (int kk = 0; kk < 8; ++kk)
#pragma unroll
      for (int j = 0; j < 2; ++j) {
        half8 bf = *(const half8*)&kcur[row512_off(j * 16 + l15, kk * 4 + quad)];
        sa[j] = __builtin_amdgcn_mfma_f32_16x16x32_f16(qf[kk], bf, sa[j], 0, 0, 0);
      }
    __builtin_amdgcn_s_setprio(0);

    // ---- softmax(it) ----
    float mt4[4];
#pragma unroll
    for (int r = 0; r < 4; ++r) mt4[r] = fmaxf(sa[0][r], sa[1][r]);
#pragma unroll
    for (int off = 1; off < 16; off <<= 1)
#pragma unroll
      for (int r = 0; r < 4; ++r)
        mt4[r] = fmaxf(mt4[r], __shfl_xor(mt4[r], off, 64));
    float alpha[4];
#pragma unroll
    for (int r = 0; r < 4; ++r) {
      float mn = fmaxf(m_i[r], mt4[r]);
      alpha[r] = __expf(m_i[r] - mn);
      m_i[r] = mn;
    }
#pragma unroll
    for (int r = 0; r < 4; ++r) {
      float ls = 0.f;
#pragma unroll
      for (int j = 0; j < 2; ++j) {
        float p = __expf(sa[j][r] - m_i[r]);
        sa[j][r] = p;
        ls += p;
      }
      lp_[r] = lp_[r] * alpha[r] + ls;
    }
    if (l15 == 0) {
      f32x4 a4 = {alpha[0], alpha[1], alpha[2], alpha[3]};
      *(f32x4*)&alc[w * 16 + quad * 4] = a4;
    }
#pragma unroll
    for (int j = 0; j < 2; ++j)
#pragma unroll
      for (int r = 0; r < 4; ++r) {
        int row = w * 16 + quad * 4 + r;
        int ch = 2 * j + (l15 >> 3);
        pcur[tile32_off(row, ch) + (l15 & 7)] = f2h(sa[j][r]);
      }

    // ---- PV(it-1) ----
    if (it > it_beg) pv_step(pprev, vprev, alp);
  }

  // ---- epilogue: final PV for tile it_end-1 ----
  {
    int par = (it_end - 1) & 1;
    __syncthreads();   // drains V(last) DMA; P(last)/alpha(last) visible
    pv_step(par ? pt1 : pt0, par ? vt1 : vt0, par ? al1 : al0);
  }

#pragma unroll
  for (int off = 1; off < 16; off <<= 1)
#pragma unroll
    for (int r = 0; r < 4; ++r)
      lp_[r] += __shfl_xor(lp_[r], off, 64);
  if (l15 == 0) {
#pragma unroll
    for (int r = 0; r < 4; ++r) ll[w * 16 + quad * 4 + r] = lp_[r];
  }
  if (n_splits != 1 && l15 == 0) {
    size_t qi = (size_t)q0 + w * 16 + quad * 4;
    float* mp = ml + ((size_t)(split * 2 + 0) * BB + b) * NN + qi;
    float* lq = ml + ((size_t)(split * 2 + 1) * BB + b) * NN + qi;
#pragma unroll
    for (int r = 0; r < 4; ++r) { mp[r] = m_i[r]; lq[r] = lp_[r]; }
  }
  __syncthreads();
  float sc[2][4];
#pragma unroll
  for (int mt = 0; mt < 2; ++mt)
#pragma unroll
    for (int r = 0; r < 4; ++r) {
      float lv = ll[g * 32 + mt * 16 + quad * 4 + r];
      sc[mt][r] = (n_splits == 1) ? 1.f / lv : 1.f;
    }

  float* od = (float*)sm;     // 32 x 132 f32 (16896 B), kt region dead
  float* obf = out + (size_t)b * CC * NN + q0;
  unsigned short* obh = opart + ((size_t)split * BB + b) * CC * NN + q0;
#pragma unroll
  for (int pp = 0; pp < 8; ++pp) {
    __syncthreads();
    if (h == (pp >> 2)) {
#pragma unroll
      for (int cp = 0; cp < 2; ++cp) {
        int ct = (pp & 3) * 2 + cp;
#pragma unroll
        for (int mt = 0; mt < 2; ++mt)
#pragma unroll
          for (int r = 0; r < 4; ++r)
            od[(cp * 16 + l15) * 132 + g * 32 + mt * 16 + quad * 4 + r] =
                o_acc[mt][ct][r] * sc[mt][r];
      }
    }
    __syncthreads();
    if (n_splits == 1) {
#pragma unroll
      for (int p2 = 0; p2 < 2; ++p2) {
        int row = p2 * 16 + (t >> 5);
        *(float4*)(obf + (size_t)(pp * 32 + row) * NN + (t & 31) * 4) =
          *(const float4*)&od[row * 132 + (t & 31) * 4];
      }
    } else {
      int row = t >> 4, q8 = (t & 15) * 8;
      union { unsigned short u[8]; uint4 v4; } tmp;
#pragma unroll
      for (int i2 = 0; i2 < 8; ++i2) tmp.u[i2] = f2h(od[row * 132 + q8 + i2]);
      *(uint4*)(obh + (size_t)(pp * 32 + row) * NN + q8) = tmp.v4;
    }
  }
}

// ---------------- merge of 2 key-splits ----------------
__global__ __launch_bounds__(256) void k_merge(const unsigned short* __restrict__ opart,
    const float* __restrict__ ml, float* __restrict__ out) {
  size_t i = ((size_t)blockIdx.x * 256 + threadIdx.x) * 4;
  int n = (int)(i & (NN - 1));
  int b = (int)(i >> 20);   // i / (CC*NN)
  float4 m1 = *(const float4*)(ml + ((size_t)(0 * BB) + b) * NN + n);
  float4 l1 = *(const float4*)(ml + ((size_t)(1 * BB) + b) * NN + n);
  float4 m2 = *(const float4*)(ml + ((size_t)(2 * BB) + b) * NN + n);
  float4 l2 = *(const float4*)(ml + ((size_t)(3 * BB) + b) * NN + n);
  ushort4 o1 = *(const ushort4*)(opart + i);
  ushort4 o2 = *(const ushort4*)(opart + (size_t)BB * CC * NN + i);
  float4 res;
#define MRG(f, comp) { \
    float M = fmaxf(m1.f, m2.f); \
    float e1 = __expf(m1.f - M), e2 = __expf(m2.f - M); \
    res.f = (e1 * h2f(o1.comp) + e2 * h2f(o2.comp)) / (e1 * l1.f + e2 * l2.f); }
  MRG(x, x) MRG(y, y) MRG(z, z) MRG(w, w)
#undef MRG
  *(float4*)(out + i) = res;
}

extern "C" void kernel_launch(void* const* d_in, const int* in_sizes, int n_in,
                              void* d_out, int out_size, void* d_ws, size_t ws_size,
                              hipStream_t stream) {
  const float* x  = (const float*)d_in[0];
  const float* Wq = (const float*)d_in[1];
  const float* bq = (const float*)d_in[2];
  const float* Wk = (const float*)d_in[3];
  const float* bk = (const float*)d_in[4];
  const float* Wv = (const float*)d_in[5];
  const float* bv = (const float*)d_in[6];
  float* out = (float*)d_out;
  char* ws = (char*)d_ws;
  const size_t MB = 1024 * 1024;
  unsigned short* Qb = (unsigned short*)(ws);             // 8 MB fp16 (B,N,C)
  unsigned short* Kb = (unsigned short*)(ws + 8 * MB);    // 8 MB fp16 (B,N,C)
  unsigned short* Vb = (unsigned short*)(ws + 16 * MB);   // 8 MB fp16 (B,C,N)
  unsigned short* Op = (unsigned short*)(ws + 24 * MB);   // 16 MB fp16 partials
  float*          Ml = (float*)(ws + 40 * MB);            // 256 KB

  int ns = (ws_size >= 41 * MB) ? 2 : 1;
  unsigned short* Wt = (unsigned short*)(ns == 2 ? ws + 40 * MB + 256 * 1024
                                                 : ws + 24 * MB);

  k_wcast<<<dim3(96), 256, 0, stream>>>(Wq, Wk, Wv, Wt);
  k_proj<<<dim3(128, 4), 512, 0, stream>>>(x, Wt, bq, bk, bv, Qb, Kb, Vb);

  k_flash<<<dim3(32, 4, ns), 512, 0, stream>>>(Qb, Kb, Vb, out, Op, Ml, ns);
  if (ns == 2) k_merge<<<dim3(4096), 256, 0, stream>>>(Op, Ml, out);
}